// Round 9
// baseline (324.485 us; speedup 1.0000x reference)
//
#include <hip/hip_runtime.h>
#include <hip/hip_bf16.h>
#include <cmath>

#define BB 4
#define SS 2048
#define DD 1024
#define BS (BB*SS)            // 8192 rows total
constexpr float EPS = 1e-6f;

typedef __attribute__((ext_vector_type(8))) short short8;
typedef __attribute__((ext_vector_type(4))) float floatx4;

__device__ inline float bf2f(unsigned short u) {
    unsigned v = ((unsigned)u) << 16;
    float f; __builtin_memcpy(&f, &v, 4);
    return f;
}

// ---------------------------------------------------------------------------
// K0 (prep): blocks [0,2048): convert Wk,Wq fp32->bf16  Wb=[Wk_bf|Wq_bf]
//            blocks [2048,2561): gemv u=Wq·bk, v=Wk·bq, cs=bq·bk
//            blocks [2561,2577): zero sacc (2*BS floats)
// ---------------------------------------------------------------------------
__global__ __launch_bounds__(256)
void prep_kernel(const float* __restrict__ Wq, const float* __restrict__ Wk,
                 const float* __restrict__ bq, const float* __restrict__ bk,
                 __hip_bfloat16* __restrict__ Wb, float* __restrict__ u,
                 float* __restrict__ v, float* __restrict__ cs,
                 float* __restrict__ sacc) {
    int blk = blockIdx.x;
    if (blk < 2048) {
        int idx = blk * 256 + threadIdx.x;          // float4 index over 2*DD*DD/4
        const int half = DD * DD / 4;
        const float* src = (idx < half) ? Wk : Wq;
        int off = (idx < half) ? idx : idx - half;
        float4 val = ((const float4*)src)[off];
        union { ushort4 uu; __hip_bfloat16 h[4]; } pk;
        pk.h[0] = __float2bfloat16(val.x);
        pk.h[1] = __float2bfloat16(val.y);
        pk.h[2] = __float2bfloat16(val.z);
        pk.h[3] = __float2bfloat16(val.w);
        ((ushort4*)Wb)[idx] = pk.uu;
    } else if (blk < 2561) {
        int gid = (blk - 2048) * 4 + (threadIdx.x >> 6);
        int lane = threadIdx.x & 63;
        if (gid > 2048) return;
        const float* row; const float* vec; float* outp;
        if (gid < 1024)      { row = Wq + (size_t)gid * DD;          vec = bk; outp = u + gid; }
        else if (gid < 2048) { row = Wk + (size_t)(gid - 1024) * DD; vec = bq; outp = v + (gid - 1024); }
        else                 { row = bq;                             vec = bk; outp = cs; }
        float s = 0.f;
        #pragma unroll
        for (int k = 0; k < 4; ++k) {
            float4 a = ((const float4*)row)[lane * 4 + k];
            float4 b = ((const float4*)vec)[lane * 4 + k];
            s += a.x * b.x + a.y * b.y + a.z * b.z + a.w * b.w;
        }
        #pragma unroll
        for (int off = 32; off; off >>= 1) s += __shfl_down(s, off);
        if (lane == 0) *outp = s;
    } else {
        int idx = (blk - 2561) * 1024 + threadIdx.x * 4;   // 16 blocks * 1024 = 16384
        *(float4*)(sacc + idx) = make_float4(0.f, 0.f, 0.f, 0.f);
    }
}

// ---------------------------------------------------------------------------
// K1: LayerNorm -> bf16 x ; fused alpha[i]=x_i·u + c, beta[i]=x_i·v
// WAVE-PER-ROW: 2048 blocks x 4 waves; each 64-lane wave owns one row.
// ---------------------------------------------------------------------------
__global__ __launch_bounds__(256)
void ln_kernel(const float* __restrict__ ctx, const float* __restrict__ gamma,
               const float* __restrict__ beta, const float* __restrict__ u,
               const float* __restrict__ v, const float* __restrict__ cs,
               __hip_bfloat16* __restrict__ xo, float* __restrict__ alpha,
               float* __restrict__ betav) {
    int wid = threadIdx.x >> 6, lane = threadIdx.x & 63;
    int row = blockIdx.x * 4 + wid;
    const float4* r = (const float4*)(ctx + (size_t)row * DD);
    float4 val[4];
    float s1 = 0.f, s2 = 0.f;
    #pragma unroll
    for (int k = 0; k < 4; ++k) {
        val[k] = r[lane + 64 * k];
        s1 += val[k].x + val[k].y + val[k].z + val[k].w;
        s2 += val[k].x * val[k].x + val[k].y * val[k].y
            + val[k].z * val[k].z + val[k].w * val[k].w;
    }
    #pragma unroll
    for (int off = 32; off; off >>= 1) {
        s1 += __shfl_down(s1, off);
        s2 += __shfl_down(s2, off);
    }
    s1 = __shfl(s1, 0);
    s2 = __shfl(s2, 0);
    float mean = s1 / DD;
    float var  = (s2 - s1 * s1 / DD) / (DD - 1);
    float rstd = 1.0f / (sqrtf(var) + EPS);
    float du = 0.f, dv = 0.f;
    ushort4* xout = (ushort4*)(xo + (size_t)row * DD);
    #pragma unroll
    for (int k = 0; k < 4; ++k) {
        int idx = lane + 64 * k;
        float4 g  = ((const float4*)gamma)[idx];
        float4 be = ((const float4*)beta)[idx];
        float nx0 = g.x * (val[k].x - mean) * rstd + be.x;
        float nx1 = g.y * (val[k].y - mean) * rstd + be.y;
        float nx2 = g.z * (val[k].z - mean) * rstd + be.z;
        float nx3 = g.w * (val[k].w - mean) * rstd + be.w;
        union { ushort4 uu; __hip_bfloat16 h[4]; } pk;
        pk.h[0] = __float2bfloat16(nx0);
        pk.h[1] = __float2bfloat16(nx1);
        pk.h[2] = __float2bfloat16(nx2);
        pk.h[3] = __float2bfloat16(nx3);
        xout[idx] = pk.uu;
        float4 u4 = ((const float4*)u)[idx];
        float4 v4 = ((const float4*)v)[idx];
        du += nx0 * u4.x + nx1 * u4.y + nx2 * u4.z + nx3 * u4.w;
        dv += nx0 * v4.x + nx1 * v4.y + nx2 * v4.z + nx3 * v4.w;
    }
    #pragma unroll
    for (int off = 32; off; off >>= 1) {
        du += __shfl_down(du, off);
        dv += __shfl_down(dv, off);
    }
    if (lane == 0) {
        alpha[row] = du + *cs;
        betav[row] = dv;
    }
}

// ---------------------------------------------------------------------------
// K2: 64x64-tile MFMA GEMM for Mt = Wk @ Wq^T, T2-swizzled, double-buffered.
// ---------------------------------------------------------------------------
__global__ __launch_bounds__(256)
void gemm64_mfma(const __hip_bfloat16* __restrict__ A,
                 const __hip_bfloat16* __restrict__ B,
                 __hip_bfloat16* __restrict__ C, int ldc) {
    __shared__ short smem[16384];            // 32 KB: 2 x (As 64x64 + Bs 64x64)
    int tid = threadIdx.x;
    int wave = tid >> 6;
    int lane = tid & 63;
    int q = lane >> 4, m16 = lane & 15;
    int srow = lane >> 3;                    // 0..7  (LDS row within 8-row stripe)
    int skoff = ((lane & 7) ^ srow) * 8;     // T2: source chunk ^= row&7

    const __hip_bfloat16* gA = A + ((size_t)blockIdx.x * 64 + wave * 16 + srow) * DD + skoff;
    const __hip_bfloat16* gB = B + ((size_t)blockIdx.y * 64 + wave * 16 + srow) * DD + skoff;

    int swr = (m16 & 7) * 8;                 // read-side involution

    floatx4 acc[4] = {};

    #define STG(p, k0) do {                                                          \
        short* As_ = smem + (p) * 8192;                                              \
        short* Bs_ = As_ + 4096;                                                     \
        __builtin_amdgcn_global_load_lds(                                            \
            (const __attribute__((address_space(1))) void*)(gA + (k0)),              \
            (__attribute__((address_space(3))) void*)(As_ + (wave * 16) * 64), 16, 0, 0); \
        __builtin_amdgcn_global_load_lds(                                            \
            (const __attribute__((address_space(1))) void*)(gA + (k0) + 8 * DD),     \
            (__attribute__((address_space(3))) void*)(As_ + (wave * 16 + 8) * 64), 16, 0, 0); \
        __builtin_amdgcn_global_load_lds(                                            \
            (const __attribute__((address_space(1))) void*)(gB + (k0)),              \
            (__attribute__((address_space(3))) void*)(Bs_ + (wave * 16) * 64), 16, 0, 0); \
        __builtin_amdgcn_global_load_lds(                                            \
            (const __attribute__((address_space(1))) void*)(gB + (k0) + 8 * DD),     \
            (__attribute__((address_space(3))) void*)(Bs_ + (wave * 16 + 8) * 64), 16, 0, 0); \
    } while (0)

    #define CMP(p) do {                                                              \
        const short* As_ = smem + (p) * 8192;                                        \
        const short* Bs_ = As_ + 4096;                                               \
        _Pragma("unroll")                                                            \
        for (int h = 0; h < 2; ++h) {                                                \
            short8 af = *(const short8*)(As_ + (wave * 16 + m16) * 64 + ((h * 32 + q * 8) ^ swr)); \
            _Pragma("unroll")                                                        \
            for (int c = 0; c < 4; ++c) {                                            \
                short8 bf_ = *(const short8*)(Bs_ + (c * 16 + m16) * 64 + ((h * 32 + q * 8) ^ swr)); \
                acc[c] = __builtin_amdgcn_mfma_f32_16x16x32_bf16(af, bf_, acc[c], 0, 0, 0); \
            }                                                                        \
        }                                                                            \
    } while (0)

    STG(0, 0);
    __syncthreads();
    for (int k0 = 0; k0 < DD; k0 += 128) {
        if (k0 + 64 < DD) STG(1, k0 + 64);
        CMP(0);
        __syncthreads();
        if (k0 + 128 < DD) STG(0, k0 + 128);
        CMP(1);
        __syncthreads();
    }
    #undef STG
    #undef CMP

    #pragma unroll
    for (int c = 0; c < 4; ++c) {
        int gcol = blockIdx.y * 64 + c * 16 + m16;
        #pragma unroll
        for (int e = 0; e < 4; ++e) {
            int grow = blockIdx.x * 64 + wave * 16 + q * 4 + e;
            C[(size_t)grow * ldc + gcol] = __float2bfloat16(acc[c][e]);
        }
    }
}

// ---------------------------------------------------------------------------
// K3: MFMA GEMM z = x @ Mt^T with FUSED band epilogue (z never stored).
// BK=64, double-buffered LDS, stage t+1 before compute t, T2 XOR-swizzle.
// ---------------------------------------------------------------------------
#define TM 128
#define TN 128
#define BK 64
__global__ __launch_bounds__(256)
void gemm2_fused(const __hip_bfloat16* __restrict__ A,    // x
                 const __hip_bfloat16* __restrict__ B,    // Mt
                 float* __restrict__ sacc) {
    __shared__ short smem[32768];            // 64 KB: 2 buffers x (A 128x64 + B 128x64)
    int tid = threadIdx.x;
    int wave = tid >> 6;
    int lane = tid & 63;
    int wm = wave >> 1, wn = wave & 1;
    int q = lane >> 4, m16 = lane & 15;

    int srow = lane >> 3;                    // 0..7  (8 lanes per 64-col row)
    int skoff = ((lane & 7) ^ srow) * 8;     // T2: source chunk ^= row&7
    const __hip_bfloat16* gA = A + ((size_t)blockIdx.x * TM + wave * 32 + srow) * DD + skoff;
    const __hip_bfloat16* gB = B + ((size_t)blockIdx.y * TN + wave * 32 + srow) * DD + skoff;

    int swr = (m16 & 7) * 8;                 // read-side involution

    floatx4 acc[4][4] = {};

    #define STAGE(p, k0) do {                                                        \
        short* As_ = smem + (p) * 16384;                                             \
        short* Bs_ = As_ + 8192;                                                     \
        _Pragma("unroll")                                                            \
        for (int i_ = 0; i_ < 4; ++i_) {                                             \
            __builtin_amdgcn_global_load_lds(                                        \
                (const __attribute__((address_space(1))) void*)(gA + (k0) + i_ * 8 * DD), \
                (__attribute__((address_space(3))) void*)(As_ + (wave * 32 + i_ * 8) * BK), 16, 0, 0); \
            __builtin_amdgcn_global_load_lds(                                        \
                (const __attribute__((address_space(1))) void*)(gB + (k0) + i_ * 8 * DD), \
                (__attribute__((address_space(3))) void*)(Bs_ + (wave * 32 + i_ * 8) * BK), 16, 0, 0); \
        }                                                                            \
    } while (0)

    #define COMPUTE(p) do {                                                          \
        const short* As_ = smem + (p) * 16384;                                       \
        const short* Bs_ = As_ + 8192;                                               \
        _Pragma("unroll")                                                            \
        for (int kk = 0; kk < 2; ++kk) {                                             \
            short8 af[4], bfr[4];                                                    \
            _Pragma("unroll")                                                        \
            for (int r = 0; r < 4; ++r)                                              \
                af[r] = *(const short8*)(As_ + (wm * 64 + r * 16 + m16) * BK + ((kk * 32 + q * 8) ^ swr)); \
            _Pragma("unroll")                                                        \
            for (int c = 0; c < 4; ++c)                                              \
                bfr[c] = *(const short8*)(Bs_ + (wn * 64 + c * 16 + m16) * BK + ((kk * 32 + q * 8) ^ swr)); \
            _Pragma("unroll")                                                        \
            for (int r = 0; r < 4; ++r)                                              \
                _Pragma("unroll")                                                    \
                for (int c = 0; c < 4; ++c)                                          \
                    acc[r][c] = __builtin_amdgcn_mfma_f32_16x16x32_bf16(af[r], bfr[c], acc[r][c], 0, 0, 0); \
        }                                                                            \
    } while (0)

    STAGE(0, 0);
    __syncthreads();
    for (int t = 0; t < DD / BK; t += 2) {
        if (t + 1 < DD / BK) STAGE(1, (t + 1) * BK);
        COMPUTE(0);
        __syncthreads();
        if (t + 2 < DD / BK) STAGE(0, (t + 2) * BK);
        COMPUTE(1);
        __syncthreads();
    }
    #undef STAGE
    #undef COMPUTE

    // stage wave's 64x64 z-tile (bf16) into LDS, stride 72 shorts
    short* EP = smem + wave * 4608;
    #pragma unroll
    for (int r = 0; r < 4; ++r)
        #pragma unroll
        for (int c = 0; c < 4; ++c)
            #pragma unroll
            for (int e = 0; e < 4; ++e) {
                __hip_bfloat16 hv = __float2bfloat16(acc[r][c][e]);
                EP[(r * 16 + q * 4 + e) * 72 + c * 16 + m16] = *(short*)&hv;
            }

    // per-lane: dot z row (64 cols) with x[row+1] and x[row-1] col-slices
    int rl = lane;
    int growZ = blockIdx.x * TM + wm * 64 + rl;
    int gcol0 = blockIdx.y * TN + wn * 64;
    bool hs = (growZ + 1 < BS);
    bool hb = (growZ >= 1);
    const short8* psup = (const short8*)(A + (size_t)(growZ + 1) * DD + gcol0);
    const short8* psub = (const short8*)(A + (size_t)(growZ - 1) * DD + gcol0);
    float sup = 0.f, sub = 0.f;
    #pragma unroll
    for (int c8 = 0; c8 < 8; ++c8) {
        short8 zz = *(const short8*)(EP + rl * 72 + c8 * 8);
        float zf[8];
        #pragma unroll
        for (int e = 0; e < 8; ++e) zf[e] = bf2f((unsigned short)zz[e]);
        if (hs) {
            short8 xx = psup[c8];
            #pragma unroll
            for (int e = 0; e < 8; ++e) sup += zf[e] * bf2f((unsigned short)xx[e]);
        }
        if (hb) {
            short8 xx = psub[c8];
            #pragma unroll
            for (int e = 0; e < 8; ++e) sub += zf[e] * bf2f((unsigned short)xx[e]);
        }
    }
    if (hs) atomicAdd(&sacc[growZ], sup);
    if (hb) atomicAdd(&sacc[BS + growZ], sub);
}

// ---------------------------------------------------------------------------
// K4: per-row 2-entry softmax from accumulated band scores (128 x 64)
// ---------------------------------------------------------------------------
__global__ __launch_bounds__(64)
void softmax_kernel(const float* __restrict__ sacc, const int* __restrict__ eos,
                    const float* __restrict__ alpha, const float* __restrict__ betav,
                    float* __restrict__ vsub, float* __restrict__ vsup,
                    float* __restrict__ wuni) {
    int gw = blockIdx.x * 64 + threadIdx.x;   // 0..BS-1
    int i = gw & (SS - 1);
    float a = alpha[gw];
    float ssup = 0.f, ssub = 0.f;
    if (i < SS - 1) ssup = (sacc[gw] + a + betav[gw + 1]) * (1.0f / DD);
    if (i > 0)      ssub = (sacc[BS + gw] + a + betav[gw - 1]) * (1.0f / DD);
    bool msub = (i > 0) && (__builtin_nontemporal_load(&eos[(size_t)gw * SS + (i - 1)]) != 0);
    bool msup = (i < SS - 1) && (__builtin_nontemporal_load(&eos[(size_t)gw * SS + (i + 1)]) != 0);
    float vs, vp, w;
    if (msub && msup) {
        float mx = fmaxf(ssub, ssup);
        float e1 = expf(ssub - mx), e2 = expf(ssup - mx);
        float inv = 1.0f / (e1 + e2);
        vs = e1 * inv; vp = e2 * inv; w = 0.f;
    } else if (msub) { vs = 1.f; vp = 0.f; w = 0.f; }
    else if (msup)   { vs = 0.f; vp = 1.f; w = 0.f; }
    else             { vs = vp = w = 1.0f / SS; }
    vsub[gw] = vs; vsup[gw] = vp; wuni[gw] = w;
}

// ---------------------------------------------------------------------------
// K5: per batch, Lc[i] = sum_{t<i} log(na3[t,t+1] + 1e-9)  (double precision)
// ---------------------------------------------------------------------------
__global__ __launch_bounds__(256)
void scan_kernel(const float* __restrict__ prior, const float* __restrict__ vsub,
                 const float* __restrict__ vsup, double* __restrict__ Lc) {
    int b = blockIdx.x;
    int t = threadIdx.x;
    double loc[8];
    double s = 0.0;
    #pragma unroll
    for (int k = 0; k < 8; ++k) {
        int tt = t * 8 + k;
        double Lv = 0.0;
        if (tt < SS - 1) {
            float pr = prior[((size_t)(b * SS + tt)) * SS + tt + 1];
            float na2 = sqrtf(vsup[b * SS + tt] * vsub[b * SS + tt + 1] + 1e-9f);
            float P = pr + (1.f - pr) * na2;
            Lv = log((double)P + 1e-9);
        }
        loc[k] = Lv; s += Lv;
    }
    __shared__ double sa[256], sb[256];
    sa[t] = s;
    __syncthreads();
    double* src = sa; double* dst = sb;
    for (int off = 1; off < 256; off <<= 1) {
        double v = src[t];
        if (t >= off) v += src[t - off];
        __syncthreads();
        dst[t] = v;
        __syncthreads();
        double* tmp = src; src = dst; dst = tmp;
    }
    double run = (t == 0) ? 0.0 : src[t - 1];
    #pragma unroll
    for (int k = 0; k < 8; ++k) {
        int idx = t * 8 + k;
        Lc[b * SS + idx] = run;   // exclusive prefix
        run += loc[k];
    }
}

// ---------------------------------------------------------------------------
// K6 v3: ONE BLOCK PER OUTPUT ROW (8192 blocks x 256 thr, 8 els/thread).
// Row-uniform values (wuni[row], Lc[row], vsub/vsup[row+-1]) hoisted to
// block-uniform scalar loads; 32 B/lane contiguous per stream (2 cache
// lines per wave per stream); prior load cached; nt stores kept.
// ---------------------------------------------------------------------------
__global__ __launch_bounds__(256)
void out_kernel(const float* __restrict__ prior, const float* __restrict__ vsub,
                const float* __restrict__ vsup, const float* __restrict__ wuni,
                const double* __restrict__ Lc, float* __restrict__ out_g,
                float* __restrict__ out_na) {
    int row = blockIdx.x;               // b*S + i
    int i = row & (SS - 1);
    int b = row >> 11;
    int j0 = threadIdx.x * 8;
    size_t base = (size_t)row * SS + j0;

    // block-uniform scalars
    float wi = wuni[row];
    double Lci = Lc[row];
    float vsub_r = vsub[row];
    float vsup_r = vsup[row];
    float vsup_rm1 = (i >= 1)      ? vsup[row - 1] : 0.f;
    float vsub_rp1 = (i < SS - 1)  ? vsub[row + 1] : 0.f;
    const double* Lcb = Lc + b * SS;
    const float*  wub = wuni + b * SS;

    floatx4 p0 = *(const floatx4*)(prior + base);
    floatx4 p1 = *(const floatx4*)(prior + base + 4);
    floatx4 w0 = *(const floatx4*)(wub + j0);
    floatx4 w1 = *(const floatx4*)(wub + j0 + 4);
    float pra[8] = {p0.x, p0.y, p0.z, p0.w, p1.x, p1.y, p1.z, p1.w};
    float wja[8] = {w0.x, w0.y, w0.z, w0.w, w1.x, w1.y, w1.z, w1.w};

    float nav[8], gv[8];
    #pragma unroll
    for (int c = 0; c < 8; ++c) {
        int j = j0 + c;
        float prod;
        if (j == i - 1)      prod = vsub_r * vsup_rm1;
        else if (j == i + 1) prod = vsup_r * vsub_rp1;
        else if (j == i)     prod = wi * wi;
        else                 prod = wi * wja[c];
        float na2 = sqrtf(prod + 1e-9f);
        float p = pra[c];
        float na3 = p + (1.f - p) * na2;
        nav[c] = na3;
        if (j == i) {
            gv[c] = na3;
        } else {
            double d = (j > i) ? (Lcb[j] - Lci) : (Lci - Lcb[j]);
            gv[c] = expf((float)d) + 1e-9f;
        }
    }
    floatx4 g0 = {gv[0], gv[1], gv[2], gv[3]};
    floatx4 g1 = {gv[4], gv[5], gv[6], gv[7]};
    floatx4 n0 = {nav[0], nav[1], nav[2], nav[3]};
    floatx4 n1 = {nav[4], nav[5], nav[6], nav[7]};
    __builtin_nontemporal_store(g0, (floatx4*)(out_g + base));
    __builtin_nontemporal_store(g1, (floatx4*)(out_g + base + 4));
    __builtin_nontemporal_store(n0, (floatx4*)(out_na + base));
    __builtin_nontemporal_store(n1, (floatx4*)(out_na + base + 4));
}

// ---------------------------------------------------------------------------
extern "C" void kernel_launch(void* const* d_in, const int* in_sizes, int n_in,
                              void* d_out, int out_size, void* d_ws, size_t ws_size,
                              hipStream_t stream) {
    const float* ctx   = (const float*)d_in[0];
    const int*   eos   = (const int*)d_in[1];
    const float* prior = (const float*)d_in[2];
    const float* Wq    = (const float*)d_in[3];
    const float* bq    = (const float*)d_in[4];
    const float* Wk    = (const float*)d_in[5];
    const float* bk    = (const float*)d_in[6];
    const float* gamma = (const float*)d_in[7];
    const float* beta  = (const float*)d_in[8];

    float* out_g  = (float*)d_out;
    float* out_na = out_g + (size_t)BB * SS * SS;

    char* ws = (char*)d_ws;
    size_t o = 0;
    __hip_bfloat16* x  = (__hip_bfloat16*)(ws + o); o += (size_t)BS * DD * 2;     // 16 MiB
    __hip_bfloat16* Wb = (__hip_bfloat16*)(ws + o); o += (size_t)2 * DD * DD * 2; // 4 MiB [Wk|Wq]
    __hip_bfloat16* Mt = (__hip_bfloat16*)(ws + o); o += (size_t)DD * DD * 2;     // 2 MiB
    double* Lc   = (double*)(ws + o); o += (size_t)BS * 8;                        // 64 KiB
    float* u     = (float*)(ws + o);  o += DD * 4;
    float* v     = (float*)(ws + o);  o += DD * 4;
    float* cs    = (float*)(ws + o);  o += 64;
    float* alpha = (float*)(ws + o);  o += (size_t)BS * 4;
    float* betav = (float*)(ws + o);  o += (size_t)BS * 4;
    float* vsub  = (float*)(ws + o);  o += (size_t)BS * 4;
    float* vsup  = (float*)(ws + o);  o += (size_t)BS * 4;
    float* wuni  = (float*)(ws + o);  o += (size_t)BS * 4;
    float* sacc  = (float*)(ws + o);  o += (size_t)2 * BS * 4;                    // 64 KiB

    __hip_bfloat16* Wk_bf = Wb;
    __hip_bfloat16* Wq_bf = Wb + (size_t)DD * DD;

    prep_kernel<<<2577, 256, 0, stream>>>(Wq, Wk, bq, bk, Wb, u, v, cs, sacc);
    ln_kernel<<<BS / 4, 256, 0, stream>>>(ctx, gamma, beta, u, v, cs, x, alpha, betav);

    // Mt[j,d] = sum_e Wk[j,e] Wq[d,e]   (1024x1024), 256 blocks
    dim3 g1(DD / 64, DD / 64);
    gemm64_mfma<<<g1, 256, 0, stream>>>(Wk_bf, Wq_bf, Mt, DD);

    // z = x @ Mt^T with fused band dot -> sacc
    dim3 g2(BS / TM, DD / TN);
    gemm2_fused<<<g2, 256, 0, stream>>>(x, Mt, sacc);

    softmax_kernel<<<BS / 64, 64, 0, stream>>>(sacc, eos, alpha, betav, vsub, vsup, wuni);

    scan_kernel<<<BB, 256, 0, stream>>>(prior, vsub, vsup, Lc);

    out_kernel<<<BS, 256, 0, stream>>>(prior, vsub, vsup, wuni, Lc, out_g, out_na);
}

// Round 10
// 317.149 us; speedup vs baseline: 1.0231x; 1.0231x over previous
//
#include <hip/hip_runtime.h>
#include <hip/hip_bf16.h>
#include <cmath>

#define BB 4
#define SS 2048
#define DD 1024
#define BS (BB*SS)            // 8192 rows total
constexpr float EPS = 1e-6f;

typedef __attribute__((ext_vector_type(8))) short short8;
typedef __attribute__((ext_vector_type(4))) float floatx4;

__device__ inline float bf2f(unsigned short u) {
    unsigned v = ((unsigned)u) << 16;
    float f; __builtin_memcpy(&f, &v, 4);
    return f;
}

// ---------------------------------------------------------------------------
// K0 (prep): blocks [0,2048): convert Wk,Wq fp32->bf16  Wb=[Wk_bf|Wq_bf]
//            blocks [2048,2561): gemv u=Wq·bk, v=Wk·bq, cs=bq·bk
//            blocks [2561,2577): zero sacc (2*BS floats)
// ---------------------------------------------------------------------------
__global__ __launch_bounds__(256)
void prep_kernel(const float* __restrict__ Wq, const float* __restrict__ Wk,
                 const float* __restrict__ bq, const float* __restrict__ bk,
                 __hip_bfloat16* __restrict__ Wb, float* __restrict__ u,
                 float* __restrict__ v, float* __restrict__ cs,
                 float* __restrict__ sacc) {
    int blk = blockIdx.x;
    if (blk < 2048) {
        int idx = blk * 256 + threadIdx.x;          // float4 index over 2*DD*DD/4
        const int half = DD * DD / 4;
        const float* src = (idx < half) ? Wk : Wq;
        int off = (idx < half) ? idx : idx - half;
        float4 val = ((const float4*)src)[off];
        union { ushort4 uu; __hip_bfloat16 h[4]; } pk;
        pk.h[0] = __float2bfloat16(val.x);
        pk.h[1] = __float2bfloat16(val.y);
        pk.h[2] = __float2bfloat16(val.z);
        pk.h[3] = __float2bfloat16(val.w);
        ((ushort4*)Wb)[idx] = pk.uu;
    } else if (blk < 2561) {
        int gid = (blk - 2048) * 4 + (threadIdx.x >> 6);
        int lane = threadIdx.x & 63;
        if (gid > 2048) return;
        const float* row; const float* vec; float* outp;
        if (gid < 1024)      { row = Wq + (size_t)gid * DD;          vec = bk; outp = u + gid; }
        else if (gid < 2048) { row = Wk + (size_t)(gid - 1024) * DD; vec = bq; outp = v + (gid - 1024); }
        else                 { row = bq;                             vec = bk; outp = cs; }
        float s = 0.f;
        #pragma unroll
        for (int k = 0; k < 4; ++k) {
            float4 a = ((const float4*)row)[lane * 4 + k];
            float4 b = ((const float4*)vec)[lane * 4 + k];
            s += a.x * b.x + a.y * b.y + a.z * b.z + a.w * b.w;
        }
        #pragma unroll
        for (int off = 32; off; off >>= 1) s += __shfl_down(s, off);
        if (lane == 0) *outp = s;
    } else {
        int idx = (blk - 2561) * 1024 + threadIdx.x * 4;   // 16 blocks * 1024 = 16384
        *(float4*)(sacc + idx) = make_float4(0.f, 0.f, 0.f, 0.f);
    }
}

// ---------------------------------------------------------------------------
// K1: LayerNorm -> bf16 x ; fused alpha[i]=x_i·u + c, beta[i]=x_i·v
// WAVE-PER-ROW: 2048 blocks x 4 waves; each 64-lane wave owns one row.
// ---------------------------------------------------------------------------
__global__ __launch_bounds__(256)
void ln_kernel(const float* __restrict__ ctx, const float* __restrict__ gamma,
               const float* __restrict__ beta, const float* __restrict__ u,
               const float* __restrict__ v, const float* __restrict__ cs,
               __hip_bfloat16* __restrict__ xo, float* __restrict__ alpha,
               float* __restrict__ betav) {
    int wid = threadIdx.x >> 6, lane = threadIdx.x & 63;
    int row = blockIdx.x * 4 + wid;
    const float4* r = (const float4*)(ctx + (size_t)row * DD);
    float4 val[4];
    float s1 = 0.f, s2 = 0.f;
    #pragma unroll
    for (int k = 0; k < 4; ++k) {
        val[k] = r[lane + 64 * k];
        s1 += val[k].x + val[k].y + val[k].z + val[k].w;
        s2 += val[k].x * val[k].x + val[k].y * val[k].y
            + val[k].z * val[k].z + val[k].w * val[k].w;
    }
    #pragma unroll
    for (int off = 32; off; off >>= 1) {
        s1 += __shfl_down(s1, off);
        s2 += __shfl_down(s2, off);
    }
    s1 = __shfl(s1, 0);
    s2 = __shfl(s2, 0);
    float mean = s1 / DD;
    float var  = (s2 - s1 * s1 / DD) / (DD - 1);
    float rstd = 1.0f / (sqrtf(var) + EPS);
    float du = 0.f, dv = 0.f;
    ushort4* xout = (ushort4*)(xo + (size_t)row * DD);
    #pragma unroll
    for (int k = 0; k < 4; ++k) {
        int idx = lane + 64 * k;
        float4 g  = ((const float4*)gamma)[idx];
        float4 be = ((const float4*)beta)[idx];
        float nx0 = g.x * (val[k].x - mean) * rstd + be.x;
        float nx1 = g.y * (val[k].y - mean) * rstd + be.y;
        float nx2 = g.z * (val[k].z - mean) * rstd + be.z;
        float nx3 = g.w * (val[k].w - mean) * rstd + be.w;
        union { ushort4 uu; __hip_bfloat16 h[4]; } pk;
        pk.h[0] = __float2bfloat16(nx0);
        pk.h[1] = __float2bfloat16(nx1);
        pk.h[2] = __float2bfloat16(nx2);
        pk.h[3] = __float2bfloat16(nx3);
        xout[idx] = pk.uu;
        float4 u4 = ((const float4*)u)[idx];
        float4 v4 = ((const float4*)v)[idx];
        du += nx0 * u4.x + nx1 * u4.y + nx2 * u4.z + nx3 * u4.w;
        dv += nx0 * v4.x + nx1 * v4.y + nx2 * v4.z + nx3 * v4.w;
    }
    #pragma unroll
    for (int off = 32; off; off >>= 1) {
        du += __shfl_down(du, off);
        dv += __shfl_down(dv, off);
    }
    if (lane == 0) {
        alpha[row] = du + *cs;
        betav[row] = dv;
    }
}

// ---------------------------------------------------------------------------
// K2: 64x64-tile MFMA GEMM for Mt = Wk @ Wq^T, T2-swizzled, double-buffered.
// ---------------------------------------------------------------------------
__global__ __launch_bounds__(256)
void gemm64_mfma(const __hip_bfloat16* __restrict__ A,
                 const __hip_bfloat16* __restrict__ B,
                 __hip_bfloat16* __restrict__ C, int ldc) {
    __shared__ short smem[16384];            // 32 KB: 2 x (As 64x64 + Bs 64x64)
    int tid = threadIdx.x;
    int wave = tid >> 6;
    int lane = tid & 63;
    int q = lane >> 4, m16 = lane & 15;
    int srow = lane >> 3;                    // 0..7  (LDS row within 8-row stripe)
    int skoff = ((lane & 7) ^ srow) * 8;     // T2: source chunk ^= row&7

    const __hip_bfloat16* gA = A + ((size_t)blockIdx.x * 64 + wave * 16 + srow) * DD + skoff;
    const __hip_bfloat16* gB = B + ((size_t)blockIdx.y * 64 + wave * 16 + srow) * DD + skoff;

    int swr = (m16 & 7) * 8;                 // read-side involution

    floatx4 acc[4] = {};

    #define STG(p, k0) do {                                                          \
        short* As_ = smem + (p) * 8192;                                              \
        short* Bs_ = As_ + 4096;                                                     \
        __builtin_amdgcn_global_load_lds(                                            \
            (const __attribute__((address_space(1))) void*)(gA + (k0)),              \
            (__attribute__((address_space(3))) void*)(As_ + (wave * 16) * 64), 16, 0, 0); \
        __builtin_amdgcn_global_load_lds(                                            \
            (const __attribute__((address_space(1))) void*)(gA + (k0) + 8 * DD),     \
            (__attribute__((address_space(3))) void*)(As_ + (wave * 16 + 8) * 64), 16, 0, 0); \
        __builtin_amdgcn_global_load_lds(                                            \
            (const __attribute__((address_space(1))) void*)(gB + (k0)),              \
            (__attribute__((address_space(3))) void*)(Bs_ + (wave * 16) * 64), 16, 0, 0); \
        __builtin_amdgcn_global_load_lds(                                            \
            (const __attribute__((address_space(1))) void*)(gB + (k0) + 8 * DD),     \
            (__attribute__((address_space(3))) void*)(Bs_ + (wave * 16 + 8) * 64), 16, 0, 0); \
    } while (0)

    #define CMP(p) do {                                                              \
        const short* As_ = smem + (p) * 8192;                                        \
        const short* Bs_ = As_ + 4096;                                               \
        _Pragma("unroll")                                                            \
        for (int h = 0; h < 2; ++h) {                                                \
            short8 af = *(const short8*)(As_ + (wave * 16 + m16) * 64 + ((h * 32 + q * 8) ^ swr)); \
            _Pragma("unroll")                                                        \
            for (int c = 0; c < 4; ++c) {                                            \
                short8 bf_ = *(const short8*)(Bs_ + (c * 16 + m16) * 64 + ((h * 32 + q * 8) ^ swr)); \
                acc[c] = __builtin_amdgcn_mfma_f32_16x16x32_bf16(af, bf_, acc[c], 0, 0, 0); \
            }                                                                        \
        }                                                                            \
    } while (0)

    STG(0, 0);
    __syncthreads();
    for (int k0 = 0; k0 < DD; k0 += 128) {
        if (k0 + 64 < DD) STG(1, k0 + 64);
        CMP(0);
        __syncthreads();
        if (k0 + 128 < DD) STG(0, k0 + 128);
        CMP(1);
        __syncthreads();
    }
    #undef STG
    #undef CMP

    #pragma unroll
    for (int c = 0; c < 4; ++c) {
        int gcol = blockIdx.y * 64 + c * 16 + m16;
        #pragma unroll
        for (int e = 0; e < 4; ++e) {
            int grow = blockIdx.x * 64 + wave * 16 + q * 4 + e;
            C[(size_t)grow * ldc + gcol] = __float2bfloat16(acc[c][e]);
        }
    }
}

// ---------------------------------------------------------------------------
// K3: MFMA GEMM z = x @ Mt^T with FUSED band epilogue (z never stored).
// BK=64, double-buffered LDS, T2 XOR-swizzle.
// v3: COUNTED-VMCNT barriers (T4): raw s_barrier + vmcnt(8) waits only for
// the buffer about to be computed; the 8 prefetch loads of the next tile
// stay in flight ACROSS the barrier (was: __syncthreads draining vmcnt(0),
// exposing full load latency every K-step). lgkmcnt(0) before the
// overwrite-releasing barrier; vmcnt(0) on the final tile; sched_barrier(0)
// fences per rule #18.
// ---------------------------------------------------------------------------
#define TM 128
#define TN 128
#define BK 64
__global__ __launch_bounds__(256)
void gemm2_fused(const __hip_bfloat16* __restrict__ A,    // x
                 const __hip_bfloat16* __restrict__ B,    // Mt
                 float* __restrict__ sacc) {
    __shared__ short smem[32768];            // 64 KB: 2 buffers x (A 128x64 + B 128x64)
    int tid = threadIdx.x;
    int wave = tid >> 6;
    int lane = tid & 63;
    int wm = wave >> 1, wn = wave & 1;
    int q = lane >> 4, m16 = lane & 15;

    int srow = lane >> 3;                    // 0..7  (8 lanes per 64-col row)
    int skoff = ((lane & 7) ^ srow) * 8;     // T2: source chunk ^= row&7
    const __hip_bfloat16* gA = A + ((size_t)blockIdx.x * TM + wave * 32 + srow) * DD + skoff;
    const __hip_bfloat16* gB = B + ((size_t)blockIdx.y * TN + wave * 32 + srow) * DD + skoff;

    int swr = (m16 & 7) * 8;                 // read-side involution

    floatx4 acc[4][4] = {};

    #define STAGE(p, k0) do {                                                        \
        short* As_ = smem + (p) * 16384;                                             \
        short* Bs_ = As_ + 8192;                                                     \
        _Pragma("unroll")                                                            \
        for (int i_ = 0; i_ < 4; ++i_) {                                             \
            __builtin_amdgcn_global_load_lds(                                        \
                (const __attribute__((address_space(1))) void*)(gA + (k0) + i_ * 8 * DD), \
                (__attribute__((address_space(3))) void*)(As_ + (wave * 32 + i_ * 8) * BK), 16, 0, 0); \
            __builtin_amdgcn_global_load_lds(                                        \
                (const __attribute__((address_space(1))) void*)(gB + (k0) + i_ * 8 * DD), \
                (__attribute__((address_space(3))) void*)(Bs_ + (wave * 32 + i_ * 8) * BK), 16, 0, 0); \
        }                                                                            \
    } while (0)

    #define COMPUTE(p) do {                                                          \
        const short* As_ = smem + (p) * 16384;                                       \
        const short* Bs_ = As_ + 8192;                                               \
        _Pragma("unroll")                                                            \
        for (int kk = 0; kk < 2; ++kk) {                                             \
            short8 af[4], bfr[4];                                                    \
            _Pragma("unroll")                                                        \
            for (int r = 0; r < 4; ++r)                                              \
                af[r] = *(const short8*)(As_ + (wm * 64 + r * 16 + m16) * BK + ((kk * 32 + q * 8) ^ swr)); \
            _Pragma("unroll")                                                        \
            for (int c = 0; c < 4; ++c)                                              \
                bfr[c] = *(const short8*)(Bs_ + (wn * 64 + c * 16 + m16) * BK + ((kk * 32 + q * 8) ^ swr)); \
            _Pragma("unroll")                                                        \
            for (int r = 0; r < 4; ++r)                                              \
                _Pragma("unroll")                                                    \
                for (int c = 0; c < 4; ++c)                                          \
                    acc[r][c] = __builtin_amdgcn_mfma_f32_16x16x32_bf16(af[r], bfr[c], acc[r][c], 0, 0, 0); \
        }                                                                            \
    } while (0)

    // counted-wait helpers (rule #18: sched_barrier after every inline waitcnt)
    #define WAIT_VM8()  do { asm volatile("s_waitcnt vmcnt(8)" ::: "memory");  __builtin_amdgcn_sched_barrier(0); } while (0)
    #define WAIT_VM0()  do { asm volatile("s_waitcnt vmcnt(0)" ::: "memory");  __builtin_amdgcn_sched_barrier(0); } while (0)
    #define WAIT_LG0()  do { asm volatile("s_waitcnt lgkmcnt(0)" ::: "memory"); __builtin_amdgcn_sched_barrier(0); } while (0)
    #define BAR()       do { __builtin_amdgcn_s_barrier(); __builtin_amdgcn_sched_barrier(0); } while (0)

    const int NT = DD / BK;                  // 16 K-tiles
    STAGE(0, 0);                             // 8 loads in flight (buf0)
    for (int t = 0; t < NT; t += 2) {
        if (t + 1 < NT) {
            STAGE(1, (t + 1) * BK);          // +8 loads (buf1): 16 outstanding
            WAIT_VM8();                      // oldest 8 (buf0) landed; buf1 in flight
        } else {
            WAIT_VM0();
        }
        BAR();                               // all waves: buf0 ready
        COMPUTE(0);
        WAIT_LG0();                          // my ds_reads of buf0 complete
        BAR();                               // all waves done with buf0 -> overwrite ok
        if (t + 2 < NT) {
            STAGE(0, (t + 2) * BK);          // +8 loads (buf0'): 16 outstanding
            WAIT_VM8();                      // oldest 8 (buf1) landed
        } else {
            WAIT_VM0();
        }
        BAR();                               // all waves: buf1 ready
        COMPUTE(1);
        WAIT_LG0();
        BAR();
    }
    #undef STAGE
    #undef COMPUTE
    #undef WAIT_VM8
    #undef WAIT_VM0
    #undef WAIT_LG0
    #undef BAR

    // stage wave's 64x64 z-tile (bf16) into LDS, stride 72 shorts
    short* EP = smem + wave * 4608;
    #pragma unroll
    for (int r = 0; r < 4; ++r)
        #pragma unroll
        for (int c = 0; c < 4; ++c)
            #pragma unroll
            for (int e = 0; e < 4; ++e) {
                __hip_bfloat16 hv = __float2bfloat16(acc[r][c][e]);
                EP[(r * 16 + q * 4 + e) * 72 + c * 16 + m16] = *(short*)&hv;
            }

    // per-lane: dot z row (64 cols) with x[row+1] and x[row-1] col-slices
    int rl = lane;
    int growZ = blockIdx.x * TM + wm * 64 + rl;
    int gcol0 = blockIdx.y * TN + wn * 64;
    bool hs = (growZ + 1 < BS);
    bool hb = (growZ >= 1);
    const short8* psup = (const short8*)(A + (size_t)(growZ + 1) * DD + gcol0);
    const short8* psub = (const short8*)(A + (size_t)(growZ - 1) * DD + gcol0);
    float sup = 0.f, sub = 0.f;
    #pragma unroll
    for (int c8 = 0; c8 < 8; ++c8) {
        short8 zz = *(const short8*)(EP + rl * 72 + c8 * 8);
        float zf[8];
        #pragma unroll
        for (int e = 0; e < 8; ++e) zf[e] = bf2f((unsigned short)zz[e]);
        if (hs) {
            short8 xx = psup[c8];
            #pragma unroll
            for (int e = 0; e < 8; ++e) sup += zf[e] * bf2f((unsigned short)xx[e]);
        }
        if (hb) {
            short8 xx = psub[c8];
            #pragma unroll
            for (int e = 0; e < 8; ++e) sub += zf[e] * bf2f((unsigned short)xx[e]);
        }
    }
    if (hs) atomicAdd(&sacc[growZ], sup);
    if (hb) atomicAdd(&sacc[BS + growZ], sub);
}

// ---------------------------------------------------------------------------
// K4: per-row 2-entry softmax from accumulated band scores (128 x 64)
// ---------------------------------------------------------------------------
__global__ __launch_bounds__(64)
void softmax_kernel(const float* __restrict__ sacc, const int* __restrict__ eos,
                    const float* __restrict__ alpha, const float* __restrict__ betav,
                    float* __restrict__ vsub, float* __restrict__ vsup,
                    float* __restrict__ wuni) {
    int gw = blockIdx.x * 64 + threadIdx.x;   // 0..BS-1
    int i = gw & (SS - 1);
    float a = alpha[gw];
    float ssup = 0.f, ssub = 0.f;
    if (i < SS - 1) ssup = (sacc[gw] + a + betav[gw + 1]) * (1.0f / DD);
    if (i > 0)      ssub = (sacc[BS + gw] + a + betav[gw - 1]) * (1.0f / DD);
    bool msub = (i > 0) && (__builtin_nontemporal_load(&eos[(size_t)gw * SS + (i - 1)]) != 0);
    bool msup = (i < SS - 1) && (__builtin_nontemporal_load(&eos[(size_t)gw * SS + (i + 1)]) != 0);
    float vs, vp, w;
    if (msub && msup) {
        float mx = fmaxf(ssub, ssup);
        float e1 = expf(ssub - mx), e2 = expf(ssup - mx);
        float inv = 1.0f / (e1 + e2);
        vs = e1 * inv; vp = e2 * inv; w = 0.f;
    } else if (msub) { vs = 1.f; vp = 0.f; w = 0.f; }
    else if (msup)   { vs = 0.f; vp = 1.f; w = 0.f; }
    else             { vs = vp = w = 1.0f / SS; }
    vsub[gw] = vs; vsup[gw] = vp; wuni[gw] = w;
}

// ---------------------------------------------------------------------------
// K5: per batch, Lc[i] = sum_{t<i} log(na3[t,t+1] + 1e-9)  (double precision)
// ---------------------------------------------------------------------------
__global__ __launch_bounds__(256)
void scan_kernel(const float* __restrict__ prior, const float* __restrict__ vsub,
                 const float* __restrict__ vsup, double* __restrict__ Lc) {
    int b = blockIdx.x;
    int t = threadIdx.x;
    double loc[8];
    double s = 0.0;
    #pragma unroll
    for (int k = 0; k < 8; ++k) {
        int tt = t * 8 + k;
        double Lv = 0.0;
        if (tt < SS - 1) {
            float pr = prior[((size_t)(b * SS + tt)) * SS + tt + 1];
            float na2 = sqrtf(vsup[b * SS + tt] * vsub[b * SS + tt + 1] + 1e-9f);
            float P = pr + (1.f - pr) * na2;
            Lv = log((double)P + 1e-9);
        }
        loc[k] = Lv; s += Lv;
    }
    __shared__ double sa[256], sb[256];
    sa[t] = s;
    __syncthreads();
    double* src = sa; double* dst = sb;
    for (int off = 1; off < 256; off <<= 1) {
        double v = src[t];
        if (t >= off) v += src[t - off];
        __syncthreads();
        dst[t] = v;
        __syncthreads();
        double* tmp = src; src = dst; dst = tmp;
    }
    double run = (t == 0) ? 0.0 : src[t - 1];
    #pragma unroll
    for (int k = 0; k < 8; ++k) {
        int idx = t * 8 + k;
        Lc[b * SS + idx] = run;   // exclusive prefix
        run += loc[k];
    }
}

// ---------------------------------------------------------------------------
// K6: fused output pass (R6-verified version): 16384 blocks x 256, 4 cols
// per thread; nt on prior load + output stores.
// ---------------------------------------------------------------------------
__global__ __launch_bounds__(256)
void out_kernel(const float* __restrict__ prior, const float* __restrict__ vsub,
                const float* __restrict__ vsup, const float* __restrict__ wuni,
                const double* __restrict__ Lc, float* __restrict__ out_g,
                float* __restrict__ out_na) {
    size_t gid = (size_t)blockIdx.x * 256 + threadIdx.x;   // 0 .. B*S*S/4-1
    int jt = (int)(gid & 511);
    int row = (int)(gid >> 9);          // b*S + i
    int i = row & (SS - 1);
    int b = row >> 11;
    int j0 = jt * 4;
    size_t base = (size_t)row * SS + j0;
    floatx4 pr4 = __builtin_nontemporal_load((const floatx4*)(prior + base));
    float4 wj4 = *(const float4*)(wuni + b * SS + j0);
    float pra[4] = {pr4.x, pr4.y, pr4.z, pr4.w};
    float wja[4] = {wj4.x, wj4.y, wj4.z, wj4.w};
    float wi = wuni[row];
    double Lci = Lc[row];
    const double* Lcb = Lc + b * SS;
    float nav[4], gv[4];
    #pragma unroll
    for (int c = 0; c < 4; ++c) {
        int j = j0 + c;
        float prod;
        if (j == i - 1)      prod = vsub[row] * vsup[row - 1];
        else if (j == i + 1) prod = vsup[row] * vsub[row + 1];
        else if (j == i)     prod = wi * wi;
        else                 prod = wi * wja[c];
        float na2 = sqrtf(prod + 1e-9f);
        float p = pra[c];
        float na3 = p + (1.f - p) * na2;
        nav[c] = na3;
        if (j == i) {
            gv[c] = na3;
        } else {
            double d = (j > i) ? (Lcb[j] - Lci) : (Lci - Lcb[j]);
            gv[c] = expf((float)d) + 1e-9f;
        }
    }
    floatx4 gq = { gv[0], gv[1], gv[2], gv[3] };
    floatx4 nq = { nav[0], nav[1], nav[2], nav[3] };
    __builtin_nontemporal_store(gq, (floatx4*)(out_g + base));
    __builtin_nontemporal_store(nq, (floatx4*)(out_na + base));
}

// ---------------------------------------------------------------------------
extern "C" void kernel_launch(void* const* d_in, const int* in_sizes, int n_in,
                              void* d_out, int out_size, void* d_ws, size_t ws_size,
                              hipStream_t stream) {
    const float* ctx   = (const float*)d_in[0];
    const int*   eos   = (const int*)d_in[1];
    const float* prior = (const float*)d_in[2];
    const float* Wq    = (const float*)d_in[3];
    const float* bq    = (const float*)d_in[4];
    const float* Wk    = (const float*)d_in[5];
    const float* bk    = (const float*)d_in[6];
    const float* gamma = (const float*)d_in[7];
    const float* beta  = (const float*)d_in[8];

    float* out_g  = (float*)d_out;
    float* out_na = out_g + (size_t)BB * SS * SS;

    char* ws = (char*)d_ws;
    size_t o = 0;
    __hip_bfloat16* x  = (__hip_bfloat16*)(ws + o); o += (size_t)BS * DD * 2;     // 16 MiB
    __hip_bfloat16* Wb = (__hip_bfloat16*)(ws + o); o += (size_t)2 * DD * DD * 2; // 4 MiB [Wk|Wq]
    __hip_bfloat16* Mt = (__hip_bfloat16*)(ws + o); o += (size_t)DD * DD * 2;     // 2 MiB
    double* Lc   = (double*)(ws + o); o += (size_t)BS * 8;                        // 64 KiB
    float* u     = (float*)(ws + o);  o += DD * 4;
    float* v     = (float*)(ws + o);  o += DD * 4;
    float* cs    = (float*)(ws + o);  o += 64;
    float* alpha = (float*)(ws + o);  o += (size_t)BS * 4;
    float* betav = (float*)(ws + o);  o += (size_t)BS * 4;
    float* vsub  = (float*)(ws + o);  o += (size_t)BS * 4;
    float* vsup  = (float*)(ws + o);  o += (size_t)BS * 4;
    float* wuni  = (float*)(ws + o);  o += (size_t)BS * 4;
    float* sacc  = (float*)(ws + o);  o += (size_t)2 * BS * 4;                    // 64 KiB

    __hip_bfloat16* Wk_bf = Wb;
    __hip_bfloat16* Wq_bf = Wb + (size_t)DD * DD;

    prep_kernel<<<2577, 256, 0, stream>>>(Wq, Wk, bq, bk, Wb, u, v, cs, sacc);
    ln_kernel<<<BS / 4, 256, 0, stream>>>(ctx, gamma, beta, u, v, cs, x, alpha, betav);

    // Mt[j,d] = sum_e Wk[j,e] Wq[d,e]   (1024x1024), 256 blocks
    dim3 g1(DD / 64, DD / 64);
    gemm64_mfma<<<g1, 256, 0, stream>>>(Wk_bf, Wq_bf, Mt, DD);

    // z = x @ Mt^T with fused band dot -> sacc
    dim3 g2(BS / TM, DD / TN);
    gemm2_fused<<<g2, 256, 0, stream>>>(x, Mt, sacc);

    softmax_kernel<<<BS / 64, 64, 0, stream>>>(sacc, eos, alpha, betav, vsub, vsup, wuni);

    scan_kernel<<<BB, 256, 0, stream>>>(prior, vsub, vsup, Lc);

    size_t total = (size_t)BB * SS * SS / 4;
    out_kernel<<<(int)(total / 256), 256, 0, stream>>>(prior, vsub, vsup, wuni, Lc,
                                                       out_g, out_na);
}